// Round 11
// baseline (280.168 us; speedup 1.0000x reference)
//
#include <hip/hip_runtime.h>
#include <hip/hip_fp16.h>
#include <math.h>

#define N_NODES 100000
#define N_EDGES 1600000
#define DIN 128
#define DH 64
#define DOUT 40

#define NB 256        // dst buckets
#define BN 391        // nodes per bucket (256*391 = 100096 >= 100000)
#define CAP 8192      // staged capacity per bucket (mean 6250, sd ~79)
#define BIN_BLOCKS 256
#define EPB 6250      // edges per k_bin block (256*6250 = 1.6M)
#define GEMM1_BLOCKS ((N_NODES + 63) / 64)   // 1563

typedef unsigned short u16;
typedef unsigned int u32;
typedef float f32x4 __attribute__((ext_vector_type(4)));
typedef unsigned short u16x4 __attribute__((ext_vector_type(4)));

__device__ inline __half2 u2h(u32 u) {
    union { u32 x; __half2 h; } c; c.x = u; return c.h;
}
__device__ inline u32 h2u(__half2 h) {
    union { __half2 h; u32 x; } c; c.h = h; return c.x;
}
__device__ inline void nt_store4(float* p, float a, float b, float c, float d) {
    f32x4 t = {a, b, c, d};
    __builtin_nontemporal_store(t, (f32x4*)p);
}

// ---------------- pass A: bin edges by dst bucket + global degree histogram ----
// staged entry: src (17 bits) | dstlocal (9 bits) << 17

__global__ __launch_bounds__(256) void k_bin(const int* __restrict__ src,
                                             const int* __restrict__ dst,
                                             int* __restrict__ gcur,
                                             int* __restrict__ deg,
                                             u32* __restrict__ staged) {
    __shared__ int hist[NB];
    __shared__ int base[NB];
    __shared__ int cur[NB];
    int t = threadIdx.x;
    for (int i = t; i < NB; i += 256) { hist[i] = 0; cur[i] = 0; }
    __syncthreads();
    int e0 = blockIdx.x * EPB;
    int e1 = e0 + EPB; if (e1 > N_EDGES) e1 = N_EDGES;
    for (int e = e0 + t; e < e1; e += 256) {
        int dd = dst[e];
        atomicAdd(&hist[dd / BN], 1);
        atomicAdd(&deg[dd], 1);         // global degree (L2-resident 400 KB)
    }
    __syncthreads();
    for (int i = t; i < NB; i += 256) {
        int h = hist[i];
        base[i] = h ? atomicAdd(&gcur[i], h) : 0;
    }
    __syncthreads();
    for (int e = e0 + t; e < e1; e += 256) {
        int d = dst[e], s = src[e];
        int b = d / BN;
        int dl = d - b * BN;
        int r = base[b] + atomicAdd(&cur[b], 1);
        if (r < CAP)
            __builtin_nontemporal_store((u32)s | ((u32)dl << 17),
                                        &staged[(size_t)b * CAP + r]);
    }
}

// ---------------- fused k_mid: blocks 0..NB-1 build CSR; rest do GEMM1 --------
// csr part outputs: csr (src ids pre-scaled by 8), meta[n], dinv[n]
// gemm part: h1s = f16((x @ W1) * rsqrt(deg[row]+1))

__global__ __launch_bounds__(256) void k_mid(const int* __restrict__ gcur,
                                             const u32* __restrict__ staged,
                                             int* __restrict__ csr,
                                             int4* __restrict__ meta,
                                             float* __restrict__ dinv,
                                             const int* __restrict__ deg,
                                             const float* __restrict__ x,
                                             const float* __restrict__ W1,
                                             u16* __restrict__ h1s) {
    __shared__ __align__(16) char smem[71296];
    int t = threadIdx.x;
    int blk = blockIdx.x;

    if (blk < NB) {
        // ---------- CSR build (identical logic to R10's k_csr) ----------
        u32* sedge = (u32*)smem;                 // 32768 B
        int* lcsr  = (int*)(smem + 32768);       // 32768 B
        int* hist  = (int*)(smem + 65536);       // 1564 B
        int* lrs   = (int*)(smem + 67100);       // 1564 B
        int* cur   = (int*)(smem + 68664);       // 1564 B
        int* sbuf  = (int*)(smem + 70228);       // 1024 B
        int b = blk;

        int part = 0;
        for (int i = t; i < b; i += 256) {
            int c = gcur[i]; if (c > CAP) c = CAP;
            part += c;
        }
        sbuf[t] = part;
        __syncthreads();
        for (int off = 128; off; off >>= 1) {
            if (t < off) sbuf[t] += sbuf[t + off];
            __syncthreads();
        }
        int base_ = sbuf[0];
        __syncthreads();

        int cnt = gcur[b]; if (cnt > CAP) cnt = CAP;
        for (int i = t; i < BN; i += 256) hist[i] = 0;
        for (int i = t; i < cnt; i += 256)
            sedge[i] = __builtin_nontemporal_load(&staged[(size_t)b * CAP + i]);
        __syncthreads();
        for (int i = t; i < cnt; i += 256) atomicAdd(&hist[sedge[i] >> 17], 1);
        __syncthreads();

        int v0 = (2 * t < BN) ? hist[2 * t] : 0;
        int v1 = (2 * t + 1 < BN) ? hist[2 * t + 1] : 0;
        int s = v0 + v1;
        sbuf[t] = s;
        __syncthreads();
        for (int off = 1; off < 256; off <<= 1) {
            int add = (t >= off) ? sbuf[t - off] : 0;
            __syncthreads();
            sbuf[t] += add;
            __syncthreads();
        }
        int excl = sbuf[t] - s;
        if (2 * t < BN)     { lrs[2 * t] = excl;          cur[2 * t] = excl; }
        if (2 * t + 1 < BN) { lrs[2 * t + 1] = excl + v0; cur[2 * t + 1] = excl + v0; }
        __syncthreads();

        for (int i = t; i < cnt; i += 256) {
            u32 p = sedge[i];
            int pos = atomicAdd(&cur[p >> 17], 1);
            lcsr[pos] = (int)((p & 0x1FFFF) << 3);   // pre-scaled: uint4-row units
        }
        __syncthreads();

        for (int i = t; i < cnt; i += 256)
            __builtin_nontemporal_store(lcsr[i], &csr[base_ + i]);
        int n0 = b * BN;
        for (int i = t; i < BN; i += 256) {
            int n = n0 + i;
            if (n < N_NODES) {
                int dg = hist[i];
                float dv = rsqrtf((float)dg + 1.0f);
                meta[n] = make_int4(base_ + lrs[i], dg, __float_as_int(dv), 0);
                dinv[n] = dv;
            }
        }
    } else {
        // ---------- GEMM1 ----------
        float* xs  = (float*)smem;               // 64*140*4 = 35840 B
        float* wsh = (float*)(smem + 35840);     // 32768 B
        int row0 = (blk - NB) * 64;

        for (int it = 0; it < 8; ++it) {
            int idx = (it * 256 + t) * 4;
            int r = idx >> 7, c = idx & 127;
            float4 v = make_float4(0.f, 0.f, 0.f, 0.f);
            if (row0 + r < N_NODES) v = *(const float4*)&x[(size_t)(row0 + r) * DIN + c];
            *(float4*)&xs[r * 140 + c] = v;
        }
        for (int it = 0; it < 8; ++it) {
            int idx = (it * 256 + t) * 4;
            *(float4*)&wsh[idx] = *(const float4*)&W1[idx];
        }
        __syncthreads();

        int tr = t & 15;   // feature group
        int tc = t >> 4;   // row group
        float acc[4][4] = {};
        for (int kb = 0; kb < DIN; kb += 4) {
            float4 w0 = *(const float4*)&wsh[(kb + 0) * DH + tr * 4];
            float4 w1 = *(const float4*)&wsh[(kb + 1) * DH + tr * 4];
            float4 w2 = *(const float4*)&wsh[(kb + 2) * DH + tr * 4];
            float4 w3 = *(const float4*)&wsh[(kb + 3) * DH + tr * 4];
#pragma unroll
            for (int i = 0; i < 4; ++i) {
                float4 xv = *(const float4*)&xs[(tc * 4 + i) * 140 + kb];
                acc[i][0] += xv.x * w0.x; acc[i][1] += xv.x * w0.y;
                acc[i][2] += xv.x * w0.z; acc[i][3] += xv.x * w0.w;
                acc[i][0] += xv.y * w1.x; acc[i][1] += xv.y * w1.y;
                acc[i][2] += xv.y * w1.z; acc[i][3] += xv.y * w1.w;
                acc[i][0] += xv.z * w2.x; acc[i][1] += xv.z * w2.y;
                acc[i][2] += xv.z * w2.z; acc[i][3] += xv.z * w2.w;
                acc[i][0] += xv.w * w3.x; acc[i][1] += xv.w * w3.y;
                acc[i][2] += xv.w * w3.z; acc[i][3] += xv.w * w3.w;
            }
        }
#pragma unroll
        for (int i = 0; i < 4; ++i) {
            int row = row0 + tc * 4 + i;
            if (row < N_NODES) {
                float dv = rsqrtf((float)deg[row] + 1.0f);
                u16x4 o;
                o.x = __half_as_ushort(__float2half(acc[i][0] * dv));
                o.y = __half_as_ushort(__float2half(acc[i][1] * dv));
                o.z = __half_as_ushort(__float2half(acc[i][2] * dv));
                o.w = __half_as_ushort(__float2half(acc[i][3] * dv));
                __builtin_nontemporal_store(o, (u16x4*)&h1s[(size_t)row * DH + tr * 4]);
            }
        }
    }
}

// ---------------- agg1 (pull): h1 = relu(dinv*(sum h1s[src] + h1s[n]) + b1) ----------------
// one wave per node; lane = (edge-slot es 0..7, feature-quad fq 0..7); 16 B/lane
// gathers (uint4). CSR entries pre-scaled by 8 -> address is x + fq.

__global__ __launch_bounds__(256) void k_agg1(const u16* __restrict__ h1s,
                                              const int4* __restrict__ meta,
                                              const int* __restrict__ csr,
                                              const float* __restrict__ b1,
                                              float* __restrict__ h1) {
    int node = blockIdx.x * 4 + (threadIdx.x >> 6);
    if (node >= N_NODES) return;
    node = __builtin_amdgcn_readfirstlane(node);
    int lane = threadIdx.x & 63;
    int es = lane >> 3, fq = lane & 7;
    int4 me = meta[node];
    int s0 = me.x, d = me.y;
    float dv = __int_as_float(me.z);
    const uint4* rows = (const uint4*)h1s;  // row stride = 8 uint4 (128 B)
    __half2 A0 = __float2half2_rn(0.f), A1 = A0, A2 = A0, A3 = A0;
    if (es == 0) {
        uint4 v = rows[(u32)(node * 8 + fq)];  // self
        A0 = u2h(v.x); A1 = u2h(v.y); A2 = u2h(v.z); A3 = u2h(v.w);
    }
    for (int base = 0; base < d; base += 64) {
        int nn = d - base; if (nn > 64) nn = 64;
        int myidx = (lane < nn) ? __builtin_nontemporal_load(&csr[s0 + base + lane]) : 0;
        int j = 0;
        for (; j + 16 <= nn; j += 16) {
            int x0 = __builtin_amdgcn_ds_bpermute((j + es) * 4, myidx);
            int x1 = __builtin_amdgcn_ds_bpermute((j + 8 + es) * 4, myidx);
            uint4 v0 = rows[(u32)(x0 + fq)];
            uint4 v1 = rows[(u32)(x1 + fq)];
            A0 = __hadd2(A0, u2h(v0.x)); A1 = __hadd2(A1, u2h(v0.y));
            A2 = __hadd2(A2, u2h(v0.z)); A3 = __hadd2(A3, u2h(v0.w));
            A0 = __hadd2(A0, u2h(v1.x)); A1 = __hadd2(A1, u2h(v1.y));
            A2 = __hadd2(A2, u2h(v1.z)); A3 = __hadd2(A3, u2h(v1.w));
        }
        for (; j < nn; j += 8) {
            int x = __builtin_amdgcn_ds_bpermute((j + es) * 4, myidx);
            if (j + es < nn) {
                uint4 v = rows[(u32)(x + fq)];
                A0 = __hadd2(A0, u2h(v.x)); A1 = __hadd2(A1, u2h(v.y));
                A2 = __hadd2(A2, u2h(v.z)); A3 = __hadd2(A3, u2h(v.w));
            }
        }
    }
    // butterfly-reduce across the 8 edge slots (xor 8,16,32)
#pragma unroll
    for (int off = 8; off <= 32; off <<= 1) {
        A0 = __hadd2(A0, u2h((u32)__shfl_xor((int)h2u(A0), off, 64)));
        A1 = __hadd2(A1, u2h((u32)__shfl_xor((int)h2u(A1), off, 64)));
        A2 = __hadd2(A2, u2h((u32)__shfl_xor((int)h2u(A2), off, 64)));
        A3 = __hadd2(A3, u2h((u32)__shfl_xor((int)h2u(A3), off, 64)));
    }
    if (es == 0) {
        float4 bva = ((const float4*)b1)[fq * 2 + 0];
        float4 bvb = ((const float4*)b1)[fq * 2 + 1];
        float* dst0 = &h1[(u32)(node * 64 + fq * 8)];
        nt_store4(dst0,
                  fmaxf(__low2float(A0)  * dv + bva.x, 0.f),
                  fmaxf(__high2float(A0) * dv + bva.y, 0.f),
                  fmaxf(__low2float(A1)  * dv + bva.z, 0.f),
                  fmaxf(__high2float(A1) * dv + bva.w, 0.f));
        nt_store4(dst0 + 4,
                  fmaxf(__low2float(A2)  * dv + bvb.x, 0.f),
                  fmaxf(__high2float(A2) * dv + bvb.y, 0.f),
                  fmaxf(__low2float(A3)  * dv + bvb.z, 0.f),
                  fmaxf(__high2float(A3) * dv + bvb.w, 0.f));
    }
}

// ---------------- GEMM2: h2s = f16((h1 @ W2) * dinv[row])  [N,64-padded] ----------------
// pad (features 40..63) never read by agg2 (exec-masked) -> no zeroing needed.

__global__ __launch_bounds__(256) void k_gemm2(const float* __restrict__ h1,
                                               const float* __restrict__ W2,
                                               const float* __restrict__ dinv,
                                               u16* __restrict__ h2s) {
    __shared__ float xs[64 * 68];
    __shared__ float wsh[DH * DOUT];
    int t = threadIdx.x;
    int row0 = blockIdx.x * 64;

    for (int it = 0; it < 4; ++it) {
        int idx = (it * 256 + t) * 4;
        int r = idx >> 6, c = idx & 63;
        float4 v = make_float4(0.f, 0.f, 0.f, 0.f);
        if (row0 + r < N_NODES) v = *(const float4*)&h1[(size_t)(row0 + r) * DH + c];
        *(float4*)&xs[r * 68 + c] = v;
    }
    for (int idx = t * 4; idx < DH * DOUT; idx += 1024) {
        *(float4*)&wsh[idx] = *(const float4*)&W2[idx];
    }
    __syncthreads();

    int fg = t & 7;
    int rg = t >> 3;
    float acc[2][5] = {};
    for (int k = 0; k < DH; ++k) {
        float x0 = xs[(rg * 2 + 0) * 68 + k];
        float x1 = xs[(rg * 2 + 1) * 68 + k];
#pragma unroll
        for (int j = 0; j < 5; ++j) {
            float w = wsh[k * DOUT + fg * 5 + j];
            acc[0][j] += x0 * w;
            acc[1][j] += x1 * w;
        }
    }
#pragma unroll
    for (int i = 0; i < 2; ++i) {
        int row = row0 + rg * 2 + i;
        if (row < N_NODES) {
            float dvv = dinv[row];
#pragma unroll
            for (int j = 0; j < 5; ++j)
                __builtin_nontemporal_store(
                    (u16)__half_as_ushort(__float2half(acc[i][j] * dvv)),
                    &h2s[(size_t)row * 64 + fg * 5 + j]);
        }
    }
}

// ---------------- agg2 (pull) + bias + log_softmax ----------------
// 8-slot uint4 layout on padded rows; ONLY fq<5 lanes issue gathers.
// Fast __expf/__logf in the softmax epilogue.

__global__ __launch_bounds__(256) void k_agg2(const u16* __restrict__ h2s,
                                              const int4* __restrict__ meta,
                                              const int* __restrict__ csr,
                                              const float* __restrict__ b2,
                                              float* __restrict__ out) {
    int node = blockIdx.x * 4 + (threadIdx.x >> 6);
    if (node >= N_NODES) return;
    node = __builtin_amdgcn_readfirstlane(node);
    int lane = threadIdx.x & 63;
    int es = lane >> 3, fq = lane & 7;
    bool act = fq < 5;
    int4 me = meta[node];
    int s0 = me.x, d = me.y;
    float dv = __int_as_float(me.z);
    const uint4* rows = (const uint4*)h2s;  // padded row stride = 8 uint4
    __half2 A0 = __float2half2_rn(0.f), A1 = A0, A2 = A0, A3 = A0;
    if (es == 0 && act) {
        uint4 v = rows[(u32)(node * 8 + fq)];  // self
        A0 = u2h(v.x); A1 = u2h(v.y); A2 = u2h(v.z); A3 = u2h(v.w);
    }
    for (int base = 0; base < d; base += 64) {
        int nn = d - base; if (nn > 64) nn = 64;
        int myidx = (lane < nn) ? __builtin_nontemporal_load(&csr[s0 + base + lane]) : 0;
        int j = 0;
        for (; j + 16 <= nn; j += 16) {
            int x0 = __builtin_amdgcn_ds_bpermute((j + es) * 4, myidx);
            int x1 = __builtin_amdgcn_ds_bpermute((j + 8 + es) * 4, myidx);
            if (act) {
                uint4 v0 = rows[(u32)(x0 + fq)];
                uint4 v1 = rows[(u32)(x1 + fq)];
                A0 = __hadd2(A0, u2h(v0.x)); A1 = __hadd2(A1, u2h(v0.y));
                A2 = __hadd2(A2, u2h(v0.z)); A3 = __hadd2(A3, u2h(v0.w));
                A0 = __hadd2(A0, u2h(v1.x)); A1 = __hadd2(A1, u2h(v1.y));
                A2 = __hadd2(A2, u2h(v1.z)); A3 = __hadd2(A3, u2h(v1.w));
            }
        }
        for (; j < nn; j += 8) {
            int x = __builtin_amdgcn_ds_bpermute((j + es) * 4, myidx);
            if (act && j + es < nn) {
                uint4 v = rows[(u32)(x + fq)];
                A0 = __hadd2(A0, u2h(v.x)); A1 = __hadd2(A1, u2h(v.y));
                A2 = __hadd2(A2, u2h(v.z)); A3 = __hadd2(A3, u2h(v.w));
            }
        }
    }
    // butterfly-reduce across the 8 edge slots
#pragma unroll
    for (int off = 8; off <= 32; off <<= 1) {
        A0 = __hadd2(A0, u2h((u32)__shfl_xor((int)h2u(A0), off, 64)));
        A1 = __hadd2(A1, u2h((u32)__shfl_xor((int)h2u(A1), off, 64)));
        A2 = __hadd2(A2, u2h((u32)__shfl_xor((int)h2u(A2), off, 64)));
        A3 = __hadd2(A3, u2h((u32)__shfl_xor((int)h2u(A3), off, 64)));
    }

    // bias + log_softmax over 40 features (5 fq groups x 8)
    float4 bva = act ? ((const float4*)b2)[fq * 2 + 0] : make_float4(0.f, 0.f, 0.f, 0.f);
    float4 bvb = act ? ((const float4*)b2)[fq * 2 + 1] : make_float4(0.f, 0.f, 0.f, 0.f);
    float v0 = act ? __low2float(A0)  * dv + bva.x : -INFINITY;
    float v1 = act ? __high2float(A0) * dv + bva.y : -INFINITY;
    float v2 = act ? __low2float(A1)  * dv + bva.z : -INFINITY;
    float v3 = act ? __high2float(A1) * dv + bva.w : -INFINITY;
    float v4 = act ? __low2float(A2)  * dv + bvb.x : -INFINITY;
    float v5 = act ? __high2float(A2) * dv + bvb.y : -INFINITY;
    float v6 = act ? __low2float(A3)  * dv + bvb.z : -INFINITY;
    float v7 = act ? __high2float(A3) * dv + bvb.w : -INFINITY;
    float m = fmaxf(fmaxf(fmaxf(v0, v1), fmaxf(v2, v3)),
                    fmaxf(fmaxf(v4, v5), fmaxf(v6, v7)));
    m = fmaxf(m, __shfl_xor(m, 1, 64));
    m = fmaxf(m, __shfl_xor(m, 2, 64));
    m = fmaxf(m, __shfl_xor(m, 4, 64));
    float ex = 0.f;
    if (act) {
        ex = __expf(v0 - m) + __expf(v1 - m) + __expf(v2 - m) + __expf(v3 - m)
           + __expf(v4 - m) + __expf(v5 - m) + __expf(v6 - m) + __expf(v7 - m);
    }
    ex += __shfl_xor(ex, 1, 64);
    ex += __shfl_xor(ex, 2, 64);
    ex += __shfl_xor(ex, 4, 64);
    float lse = m + __logf(ex);
    if (es == 0 && act) {
        float* dst0 = &out[(u32)(node * 40 + fq * 8)];
        nt_store4(dst0, v0 - lse, v1 - lse, v2 - lse, v3 - lse);
        nt_store4(dst0 + 4, v4 - lse, v5 - lse, v6 - lse, v7 - lse);
    }
}

// ---------------- launch ----------------

extern "C" void kernel_launch(void* const* d_in, const int* in_sizes, int n_in,
                              void* d_out, int out_size, void* d_ws, size_t ws_size,
                              hipStream_t stream) {
    const float* x  = (const float*)d_in[0];
    const float* W1 = (const float*)d_in[1];
    const float* b1 = (const float*)d_in[2];
    const float* W2 = (const float*)d_in[3];
    const float* b2 = (const float*)d_in[4];
    const int* eidx = (const int*)d_in[5];
    const int* srcp = eidx;
    const int* dstp = eidx + N_EDGES;
    float* out = (float*)d_out;

    char* w = (char*)d_ws;
    int* gcur    = (int*)w;   w += sizeof(int) * NB;                     // 1 KB
    int* deg     = (int*)w;   w += sizeof(int) * N_NODES;                // 400 KB
    float* dinv  = (float*)w; w += sizeof(float) * N_NODES;              // 400 KB
    int4* meta   = (int4*)w;  w += sizeof(int4) * N_NODES;               // 1.6 MB (16B-aligned)
    u32* staged  = (u32*)w;   w += sizeof(u32) * (size_t)NB * CAP;       // 8 MB
    int* csr     = (int*)w;   w += sizeof(int) * N_EDGES;                // 6.4 MB
    u16* h1s     = (u16*)w;   w += sizeof(u16) * (size_t)N_NODES * DH;   // f16 [N,64]
    float* h1    = (float*)w; w += sizeof(float) * (size_t)N_NODES * DH; // f32 [N,64]
    u16* h2s     = h1s;  // alias: h1s dead after agg1; h2s is f16 [N,64-padded]

    // zero gcur + deg in one memset (contiguous)
    hipMemsetAsync(gcur, 0, sizeof(int) * (NB + N_NODES), stream);
    k_bin<<<BIN_BLOCKS, 256, 0, stream>>>(srcp, dstp, gcur, deg, staged);
    k_mid<<<NB + GEMM1_BLOCKS, 256, 0, stream>>>(gcur, staged, csr, meta, dinv,
                                                 deg, x, W1, h1s);
    k_agg1<<<(N_NODES + 3) / 4, 256, 0, stream>>>(h1s, meta, csr, b1, h1);
    k_gemm2<<<(N_NODES + 63) / 64, 256, 0, stream>>>(h1, W2, dinv, h2s);
    k_agg2<<<(N_NODES + 3) / 4, 256, 0, stream>>>(h2s, meta, csr, b2, out);
}

// Round 12
// 239.079 us; speedup vs baseline: 1.1719x; 1.1719x over previous
//
#include <hip/hip_runtime.h>
#include <hip/hip_fp16.h>
#include <math.h>

#define N_NODES 100000
#define N_EDGES 1600000
#define DIN 128
#define DH 64
#define DOUT 40

#define NB 256        // dst buckets
#define BN 391        // nodes per bucket (256*391 = 100096 >= 100000)
#define CAP 8192      // staged capacity per bucket (mean 6250, sd ~79)
#define BIN_BLOCKS 256
#define EPB 6250      // edges per k_bin block (256*6250 = 1.6M)

typedef unsigned short u16;
typedef unsigned int u32;
typedef float f32x4 __attribute__((ext_vector_type(4)));
typedef unsigned short u16x4 __attribute__((ext_vector_type(4)));

__device__ inline __half2 u2h(u32 u) {
    union { u32 x; __half2 h; } c; c.x = u; return c.h;
}
__device__ inline u32 h2u(__half2 h) {
    union { __half2 h; u32 x; } c; c.h = h; return c.x;
}
__device__ inline void nt_store4(float* p, float a, float b, float c, float d) {
    f32x4 t = {a, b, c, d};
    __builtin_nontemporal_store(t, (f32x4*)p);
}
__device__ inline float4 nt_load4(const float* p) {
    f32x4 t = __builtin_nontemporal_load((const f32x4*)p);
    return make_float4(t.x, t.y, t.z, t.w);
}

// ---------------- pass A: bin edges by dst bucket ----------------
// staged entry: src (17 bits) | dstlocal (9 bits) << 17
// NOTE: staged scatter uses REGULAR stores — L2 write-combining is essential
// for scattered 4B stores (R11's nt-scatter caused 16x write amplification).

__global__ __launch_bounds__(256) void k_bin(const int* __restrict__ src,
                                             const int* __restrict__ dst,
                                             int* __restrict__ gcur,
                                             u32* __restrict__ staged) {
    __shared__ int hist[NB];
    __shared__ int base[NB];
    __shared__ int cur[NB];
    int t = threadIdx.x;
    for (int i = t; i < NB; i += 256) { hist[i] = 0; cur[i] = 0; }
    __syncthreads();
    int e0 = blockIdx.x * EPB;
    int e1 = e0 + EPB; if (e1 > N_EDGES) e1 = N_EDGES;
    for (int e = e0 + t; e < e1; e += 256)
        atomicAdd(&hist[dst[e] / BN], 1);
    __syncthreads();
    for (int i = t; i < NB; i += 256) {
        int h = hist[i];
        base[i] = h ? atomicAdd(&gcur[i], h) : 0;
    }
    __syncthreads();
    for (int e = e0 + t; e < e1; e += 256) {
        int d = dst[e], s = src[e];
        int b = d / BN;
        int dl = d - b * BN;
        int r = base[b] + atomicAdd(&cur[b], 1);
        if (r < CAP) staged[(size_t)b * CAP + r] = (u32)s | ((u32)dl << 17);
    }
}

// ---------------- pass B: per-bucket CSR build entirely in LDS ----------------
// outputs: csr (src ids PRE-SCALED by 8 = uint4-row units), meta[n], dinv[n]

__global__ __launch_bounds__(256) void k_csr(const int* __restrict__ gcur,
                                             const u32* __restrict__ staged,
                                             int* __restrict__ csr,
                                             int4* __restrict__ meta,
                                             float* __restrict__ dinv) {
    __shared__ u32 sedge[CAP];   // 32 KB
    __shared__ int lcsr[CAP];    // 32 KB
    __shared__ int hist[BN];
    __shared__ int lrs[BN];
    __shared__ int cur[BN];
    __shared__ int sbuf[256];
    int b = blockIdx.x, t = threadIdx.x;

    // bucket base = sum of clamped counts of buckets < b (block reduce)
    int part = 0;
    for (int i = t; i < b; i += 256) {
        int c = gcur[i]; if (c > CAP) c = CAP;
        part += c;
    }
    sbuf[t] = part;
    __syncthreads();
    for (int off = 128; off; off >>= 1) {
        if (t < off) sbuf[t] += sbuf[t + off];
        __syncthreads();
    }
    int base_ = sbuf[0];
    __syncthreads();

    int cnt = gcur[b]; if (cnt > CAP) cnt = CAP;
    for (int i = t; i < BN; i += 256) hist[i] = 0;
    for (int i = t; i < cnt; i += 256)
        sedge[i] = __builtin_nontemporal_load(&staged[(size_t)b * CAP + i]);
    __syncthreads();
    for (int i = t; i < cnt; i += 256) atomicAdd(&hist[sedge[i] >> 17], 1);
    __syncthreads();

    // exclusive scan of hist[0..BN) (2 elems/thread)
    int v0 = (2 * t < BN) ? hist[2 * t] : 0;
    int v1 = (2 * t + 1 < BN) ? hist[2 * t + 1] : 0;
    int s = v0 + v1;
    sbuf[t] = s;
    __syncthreads();
    for (int off = 1; off < 256; off <<= 1) {
        int add = (t >= off) ? sbuf[t - off] : 0;
        __syncthreads();
        sbuf[t] += add;
        __syncthreads();
    }
    int excl = sbuf[t] - s;
    if (2 * t < BN)     { lrs[2 * t] = excl;      cur[2 * t] = excl; }
    if (2 * t + 1 < BN) { lrs[2 * t + 1] = excl + v0; cur[2 * t + 1] = excl + v0; }
    __syncthreads();

    // fill local CSR (random writes stay in LDS); store src*8 (uint4-row units)
    for (int i = t; i < cnt; i += 256) {
        u32 p = sedge[i];
        int pos = atomicAdd(&cur[p >> 17], 1);
        lcsr[pos] = (int)((p & 0x1FFFF) << 3);
    }
    __syncthreads();

    // coalesced writeout (regular stores: csr re-read soon by agg1 -> keep in L2)
    for (int i = t; i < cnt; i += 256) csr[base_ + i] = lcsr[i];
    int n0 = b * BN;
    for (int i = t; i < BN; i += 256) {
        int n = n0 + i;
        if (n < N_NODES) {
            int dg = hist[i];
            float dv = rsqrtf((float)dg + 1.0f);
            meta[n] = make_int4(base_ + lrs[i], dg, __float_as_int(dv), 0);
            dinv[n] = dv;
        }
    }
}

// ---------------- GEMM1: h1s = f16((x @ W1) * dinv[row])  [N,64] ----------------
// x streamed once -> nt loads; h1s written full-line coalesced -> nt stores.

__global__ __launch_bounds__(256) void k_gemm1(const float* __restrict__ x,
                                               const float* __restrict__ W1,
                                               const float* __restrict__ dinv,
                                               u16* __restrict__ h1s) {
    __shared__ float xs[64 * 140];     // 35 KB
    __shared__ float wsh[DIN * DH];    // 32 KB
    int t = threadIdx.x;
    int row0 = blockIdx.x * 64;

    for (int it = 0; it < 8; ++it) {
        int idx = (it * 256 + t) * 4;
        int r = idx >> 7, c = idx & 127;
        float4 v = make_float4(0.f, 0.f, 0.f, 0.f);
        if (row0 + r < N_NODES) v = nt_load4(&x[(size_t)(row0 + r) * DIN + c]);
        *(float4*)&xs[r * 140 + c] = v;
    }
    for (int it = 0; it < 8; ++it) {
        int idx = (it * 256 + t) * 4;
        *(float4*)&wsh[idx] = *(const float4*)&W1[idx];
    }
    __syncthreads();

    int tr = t & 15;   // feature group: features tr*4..tr*4+3
    int tc = t >> 4;   // row group: rows tc*4..tc*4+3
    float acc[4][4] = {};
    for (int kb = 0; kb < DIN; kb += 4) {
        float4 w0 = *(const float4*)&wsh[(kb + 0) * DH + tr * 4];
        float4 w1 = *(const float4*)&wsh[(kb + 1) * DH + tr * 4];
        float4 w2 = *(const float4*)&wsh[(kb + 2) * DH + tr * 4];
        float4 w3 = *(const float4*)&wsh[(kb + 3) * DH + tr * 4];
#pragma unroll
        for (int i = 0; i < 4; ++i) {
            float4 xv = *(const float4*)&xs[(tc * 4 + i) * 140 + kb];
            acc[i][0] += xv.x * w0.x; acc[i][1] += xv.x * w0.y;
            acc[i][2] += xv.x * w0.z; acc[i][3] += xv.x * w0.w;
            acc[i][0] += xv.y * w1.x; acc[i][1] += xv.y * w1.y;
            acc[i][2] += xv.y * w1.z; acc[i][3] += xv.y * w1.w;
            acc[i][0] += xv.z * w2.x; acc[i][1] += xv.z * w2.y;
            acc[i][2] += xv.z * w2.z; acc[i][3] += xv.z * w2.w;
            acc[i][0] += xv.w * w3.x; acc[i][1] += xv.w * w3.y;
            acc[i][2] += xv.w * w3.z; acc[i][3] += xv.w * w3.w;
        }
    }
#pragma unroll
    for (int i = 0; i < 4; ++i) {
        int row = row0 + tc * 4 + i;
        if (row < N_NODES) {
            float dv = dinv[row];
            u16x4 o;
            o.x = __half_as_ushort(__float2half(acc[i][0] * dv));
            o.y = __half_as_ushort(__float2half(acc[i][1] * dv));
            o.z = __half_as_ushort(__float2half(acc[i][2] * dv));
            o.w = __half_as_ushort(__float2half(acc[i][3] * dv));
            __builtin_nontemporal_store(o, (u16x4*)&h1s[(size_t)row * DH + tr * 4]);
        }
    }
}

// ---------------- agg1 (pull): h1 = relu(dinv*(sum h1s[src] + h1s[n]) + b1) ----------------
// one wave per node; lane = (edge-slot es 0..7, feature-quad fq 0..7); 16 B/lane
// gathers (uint4). CSR pre-scaled by 8 -> address is x + fq. csr nt-loaded
// (streamed once), h1 nt-stored (contiguous 256 B/wave).

__global__ __launch_bounds__(256) void k_agg1(const u16* __restrict__ h1s,
                                              const int4* __restrict__ meta,
                                              const int* __restrict__ csr,
                                              const float* __restrict__ b1,
                                              float* __restrict__ h1) {
    int node = blockIdx.x * 4 + (threadIdx.x >> 6);
    if (node >= N_NODES) return;
    node = __builtin_amdgcn_readfirstlane(node);
    int lane = threadIdx.x & 63;
    int es = lane >> 3, fq = lane & 7;
    int4 me = meta[node];
    int s0 = me.x, d = me.y;
    float dv = __int_as_float(me.z);
    const uint4* rows = (const uint4*)h1s;  // row stride = 8 uint4 (128 B)
    __half2 A0 = __float2half2_rn(0.f), A1 = A0, A2 = A0, A3 = A0;
    if (es == 0) {
        uint4 v = rows[(u32)(node * 8 + fq)];  // self
        A0 = u2h(v.x); A1 = u2h(v.y); A2 = u2h(v.z); A3 = u2h(v.w);
    }
    for (int base = 0; base < d; base += 64) {
        int nn = d - base; if (nn > 64) nn = 64;
        int myidx = (lane < nn) ? __builtin_nontemporal_load(&csr[s0 + base + lane]) : 0;
        int j = 0;
        for (; j + 16 <= nn; j += 16) {
            int x0 = __builtin_amdgcn_ds_bpermute((j + es) * 4, myidx);
            int x1 = __builtin_amdgcn_ds_bpermute((j + 8 + es) * 4, myidx);
            uint4 v0 = rows[(u32)(x0 + fq)];
            uint4 v1 = rows[(u32)(x1 + fq)];
            A0 = __hadd2(A0, u2h(v0.x)); A1 = __hadd2(A1, u2h(v0.y));
            A2 = __hadd2(A2, u2h(v0.z)); A3 = __hadd2(A3, u2h(v0.w));
            A0 = __hadd2(A0, u2h(v1.x)); A1 = __hadd2(A1, u2h(v1.y));
            A2 = __hadd2(A2, u2h(v1.z)); A3 = __hadd2(A3, u2h(v1.w));
        }
        for (; j < nn; j += 8) {
            int x = __builtin_amdgcn_ds_bpermute((j + es) * 4, myidx);
            if (j + es < nn) {
                uint4 v = rows[(u32)(x + fq)];
                A0 = __hadd2(A0, u2h(v.x)); A1 = __hadd2(A1, u2h(v.y));
                A2 = __hadd2(A2, u2h(v.z)); A3 = __hadd2(A3, u2h(v.w));
            }
        }
    }
    // butterfly-reduce across the 8 edge slots (xor 8,16,32)
#pragma unroll
    for (int off = 8; off <= 32; off <<= 1) {
        A0 = __hadd2(A0, u2h((u32)__shfl_xor((int)h2u(A0), off, 64)));
        A1 = __hadd2(A1, u2h((u32)__shfl_xor((int)h2u(A1), off, 64)));
        A2 = __hadd2(A2, u2h((u32)__shfl_xor((int)h2u(A2), off, 64)));
        A3 = __hadd2(A3, u2h((u32)__shfl_xor((int)h2u(A3), off, 64)));
    }
    if (es == 0) {
        float4 bva = ((const float4*)b1)[fq * 2 + 0];
        float4 bvb = ((const float4*)b1)[fq * 2 + 1];
        float* dst0 = &h1[(u32)(node * 64 + fq * 8)];
        nt_store4(dst0,
                  fmaxf(__low2float(A0)  * dv + bva.x, 0.f),
                  fmaxf(__high2float(A0) * dv + bva.y, 0.f),
                  fmaxf(__low2float(A1)  * dv + bva.z, 0.f),
                  fmaxf(__high2float(A1) * dv + bva.w, 0.f));
        nt_store4(dst0 + 4,
                  fmaxf(__low2float(A2)  * dv + bvb.x, 0.f),
                  fmaxf(__high2float(A2) * dv + bvb.y, 0.f),
                  fmaxf(__low2float(A3)  * dv + bvb.z, 0.f),
                  fmaxf(__high2float(A3) * dv + bvb.w, 0.f));
    }
}

// ---------------- GEMM2: h2s = f16((h1 @ W2) * dinv[row])  [N,64-padded] ----------------
// h1 streamed once -> nt loads; h2s stores scattered u16 -> REGULAR stores.

__global__ __launch_bounds__(256) void k_gemm2(const float* __restrict__ h1,
                                               const float* __restrict__ W2,
                                               const float* __restrict__ dinv,
                                               u16* __restrict__ h2s) {
    __shared__ float xs[64 * 68];
    __shared__ float wsh[DH * DOUT];
    int t = threadIdx.x;
    int row0 = blockIdx.x * 64;

    for (int it = 0; it < 4; ++it) {
        int idx = (it * 256 + t) * 4;
        int r = idx >> 6, c = idx & 63;
        float4 v = make_float4(0.f, 0.f, 0.f, 0.f);
        if (row0 + r < N_NODES) v = nt_load4(&h1[(size_t)(row0 + r) * DH + c]);
        *(float4*)&xs[r * 68 + c] = v;
    }
    for (int idx = t * 4; idx < DH * DOUT; idx += 1024) {
        *(float4*)&wsh[idx] = *(const float4*)&W2[idx];
    }
    __syncthreads();

    int fg = t & 7;
    int rg = t >> 3;
    float acc[2][5] = {};
    for (int k = 0; k < DH; ++k) {
        float x0 = xs[(rg * 2 + 0) * 68 + k];
        float x1 = xs[(rg * 2 + 1) * 68 + k];
#pragma unroll
        for (int j = 0; j < 5; ++j) {
            float w = wsh[k * DOUT + fg * 5 + j];
            acc[0][j] += x0 * w;
            acc[1][j] += x1 * w;
        }
    }
#pragma unroll
    for (int i = 0; i < 2; ++i) {
        int row = row0 + rg * 2 + i;
        if (row < N_NODES) {
            float dvv = dinv[row];
#pragma unroll
            for (int j = 0; j < 5; ++j)
                h2s[(size_t)row * 64 + fg * 5 + j] =
                    __half_as_ushort(__float2half(acc[i][j] * dvv));
        }
    }
}

// ---------------- agg2 (pull) + bias + log_softmax ----------------
// 8-slot uint4 layout on padded rows; ONLY fq<5 lanes issue gathers.
// Fast __expf/__logf; csr nt-loaded; out nt-stored.

__global__ __launch_bounds__(256) void k_agg2(const u16* __restrict__ h2s,
                                              const int4* __restrict__ meta,
                                              const int* __restrict__ csr,
                                              const float* __restrict__ b2,
                                              float* __restrict__ out) {
    int node = blockIdx.x * 4 + (threadIdx.x >> 6);
    if (node >= N_NODES) return;
    node = __builtin_amdgcn_readfirstlane(node);
    int lane = threadIdx.x & 63;
    int es = lane >> 3, fq = lane & 7;
    bool act = fq < 5;
    int4 me = meta[node];
    int s0 = me.x, d = me.y;
    float dv = __int_as_float(me.z);
    const uint4* rows = (const uint4*)h2s;  // padded row stride = 8 uint4
    __half2 A0 = __float2half2_rn(0.f), A1 = A0, A2 = A0, A3 = A0;
    if (es == 0 && act) {
        uint4 v = rows[(u32)(node * 8 + fq)];  // self
        A0 = u2h(v.x); A1 = u2h(v.y); A2 = u2h(v.z); A3 = u2h(v.w);
    }
    for (int base = 0; base < d; base += 64) {
        int nn = d - base; if (nn > 64) nn = 64;
        int myidx = (lane < nn) ? __builtin_nontemporal_load(&csr[s0 + base + lane]) : 0;
        int j = 0;
        for (; j + 16 <= nn; j += 16) {
            int x0 = __builtin_amdgcn_ds_bpermute((j + es) * 4, myidx);
            int x1 = __builtin_amdgcn_ds_bpermute((j + 8 + es) * 4, myidx);
            if (act) {
                uint4 v0 = rows[(u32)(x0 + fq)];
                uint4 v1 = rows[(u32)(x1 + fq)];
                A0 = __hadd2(A0, u2h(v0.x)); A1 = __hadd2(A1, u2h(v0.y));
                A2 = __hadd2(A2, u2h(v0.z)); A3 = __hadd2(A3, u2h(v0.w));
                A0 = __hadd2(A0, u2h(v1.x)); A1 = __hadd2(A1, u2h(v1.y));
                A2 = __hadd2(A2, u2h(v1.z)); A3 = __hadd2(A3, u2h(v1.w));
            }
        }
        for (; j < nn; j += 8) {
            int x = __builtin_amdgcn_ds_bpermute((j + es) * 4, myidx);
            if (act && j + es < nn) {
                uint4 v = rows[(u32)(x + fq)];
                A0 = __hadd2(A0, u2h(v.x)); A1 = __hadd2(A1, u2h(v.y));
                A2 = __hadd2(A2, u2h(v.z)); A3 = __hadd2(A3, u2h(v.w));
            }
        }
    }
    // butterfly-reduce across the 8 edge slots
#pragma unroll
    for (int off = 8; off <= 32; off <<= 1) {
        A0 = __hadd2(A0, u2h((u32)__shfl_xor((int)h2u(A0), off, 64)));
        A1 = __hadd2(A1, u2h((u32)__shfl_xor((int)h2u(A1), off, 64)));
        A2 = __hadd2(A2, u2h((u32)__shfl_xor((int)h2u(A2), off, 64)));
        A3 = __hadd2(A3, u2h((u32)__shfl_xor((int)h2u(A3), off, 64)));
    }

    // bias + log_softmax over 40 features (5 fq groups x 8)
    float4 bva = act ? ((const float4*)b2)[fq * 2 + 0] : make_float4(0.f, 0.f, 0.f, 0.f);
    float4 bvb = act ? ((const float4*)b2)[fq * 2 + 1] : make_float4(0.f, 0.f, 0.f, 0.f);
    float v0 = act ? __low2float(A0)  * dv + bva.x : -INFINITY;
    float v1 = act ? __high2float(A0) * dv + bva.y : -INFINITY;
    float v2 = act ? __low2float(A1)  * dv + bva.z : -INFINITY;
    float v3 = act ? __high2float(A1) * dv + bva.w : -INFINITY;
    float v4 = act ? __low2float(A2)  * dv + bvb.x : -INFINITY;
    float v5 = act ? __high2float(A2) * dv + bvb.y : -INFINITY;
    float v6 = act ? __low2float(A3)  * dv + bvb.z : -INFINITY;
    float v7 = act ? __high2float(A3) * dv + bvb.w : -INFINITY;
    float m = fmaxf(fmaxf(fmaxf(v0, v1), fmaxf(v2, v3)),
                    fmaxf(fmaxf(v4, v5), fmaxf(v6, v7)));
    m = fmaxf(m, __shfl_xor(m, 1, 64));
    m = fmaxf(m, __shfl_xor(m, 2, 64));
    m = fmaxf(m, __shfl_xor(m, 4, 64));
    float ex = 0.f;
    if (act) {
        ex = __expf(v0 - m) + __expf(v1 - m) + __expf(v2 - m) + __expf(v3 - m)
           + __expf(v4 - m) + __expf(v5 - m) + __expf(v6 - m) + __expf(v7 - m);
    }
    ex += __shfl_xor(ex, 1, 64);
    ex += __shfl_xor(ex, 2, 64);
    ex += __shfl_xor(ex, 4, 64);
    float lse = m + __logf(ex);
    if (es == 0 && act) {
        float* dst0 = &out[(u32)(node * 40 + fq * 8)];
        nt_store4(dst0, v0 - lse, v1 - lse, v2 - lse, v3 - lse);
        nt_store4(dst0 + 4, v4 - lse, v5 - lse, v6 - lse, v7 - lse);
    }
}

// ---------------- launch ----------------

extern "C" void kernel_launch(void* const* d_in, const int* in_sizes, int n_in,
                              void* d_out, int out_size, void* d_ws, size_t ws_size,
                              hipStream_t stream) {
    const float* x  = (const float*)d_in[0];
    const float* W1 = (const float*)d_in[1];
    const float* b1 = (const float*)d_in[2];
    const float* W2 = (const float*)d_in[3];
    const float* b2 = (const float*)d_in[4];
    const int* eidx = (const int*)d_in[5];
    const int* srcp = eidx;
    const int* dstp = eidx + N_EDGES;
    float* out = (float*)d_out;

    char* w = (char*)d_ws;
    int* gcur    = (int*)w;   w += sizeof(int) * NB;
    float* dinv  = (float*)w; w += sizeof(float) * N_NODES + 48;  // keep int4 alignment
    int4* meta   = (int4*)w;  w += sizeof(int4) * N_NODES;
    u32* staged  = (u32*)w;   w += sizeof(u32) * (size_t)NB * CAP;       // 8 MB
    int* csr     = (int*)w;   w += sizeof(int) * N_EDGES;                // 6.4 MB
    u16* h1s     = (u16*)w;   w += sizeof(u16) * (size_t)N_NODES * DH;   // f16 [N,64]
    float* h1    = (float*)w; w += sizeof(float) * (size_t)N_NODES * DH; // f32 [N,64]
    u16* h2s     = h1s;  // alias: h1s dead after agg1; h2s is f16 [N,64-padded]

    hipMemsetAsync(gcur, 0, sizeof(int) * NB, stream);
    k_bin<<<BIN_BLOCKS, 256, 0, stream>>>(srcp, dstp, gcur, staged);
    k_csr<<<NB, 256, 0, stream>>>(gcur, staged, csr, meta, dinv);
    k_gemm1<<<(N_NODES + 63) / 64, 256, 0, stream>>>(x, W1, dinv, h1s);
    k_agg1<<<(N_NODES + 3) / 4, 256, 0, stream>>>(h1s, meta, csr, b1, h1);
    k_gemm2<<<(N_NODES + 63) / 64, 256, 0, stream>>>(h1, W2, dinv, h2s);
    k_agg2<<<(N_NODES + 3) / 4, 256, 0, stream>>>(h2s, meta, csr, b2, out);
}

// Round 13
// 202.974 us; speedup vs baseline: 1.3803x; 1.1779x over previous
//
#include <hip/hip_runtime.h>
#include <hip/hip_fp16.h>
#include <math.h>

#define N_NODES 100000
#define N_EDGES 1600000
#define DIN 128
#define DH 64
#define DOUT 40

#define NB 256        // dst buckets
#define BN 391        // nodes per bucket (256*391 = 100096 >= 100000)
#define CAP 8192      // staged capacity per bucket (mean 6250, sd ~79)
#define BIN_BLOCKS 256
#define EPB 6250      // edges per k_bin block (256*6250 = 1.6M)

typedef unsigned short u16;
typedef unsigned int u32;

__device__ inline __half2 u2h(u32 u) {
    union { u32 x; __half2 h; } c; c.x = u; return c.h;
}
__device__ inline u32 h2u(__half2 h) {
    union { __half2 h; u32 x; } c; c.h = h; return c.x;
}

// ---------------- pass A: bin edges by dst bucket ----------------
// staged entry: src (17 bits) | dstlocal (9 bits) << 17
// 1024 threads/block: k_bin is a latency-bound scatter; at 256 blocks that is
// 1 block/CU, so wide blocks are the only way to get TLP (16 waves/CU vs 4).
// Scatter uses REGULAR stores — L2 write-combining is essential for 4B
// scattered stores (R11's nt-scatter caused 16x write amplification).

__global__ __launch_bounds__(1024) void k_bin(const int* __restrict__ src,
                                              const int* __restrict__ dst,
                                              int* __restrict__ gcur,
                                              u32* __restrict__ staged) {
    __shared__ int hist[NB];
    __shared__ int base[NB];
    __shared__ int cur[NB];
    int t = threadIdx.x;
    for (int i = t; i < NB; i += 1024) { hist[i] = 0; cur[i] = 0; }
    __syncthreads();
    int e0 = blockIdx.x * EPB;
    int e1 = e0 + EPB; if (e1 > N_EDGES) e1 = N_EDGES;
    for (int e = e0 + t; e < e1; e += 1024)
        atomicAdd(&hist[dst[e] / BN], 1);
    __syncthreads();
    for (int i = t; i < NB; i += 1024) {
        int h = hist[i];
        base[i] = h ? atomicAdd(&gcur[i], h) : 0;
    }
    __syncthreads();
    for (int e = e0 + t; e < e1; e += 1024) {
        int d = dst[e], s = src[e];
        int b = d / BN;
        int dl = d - b * BN;
        int r = base[b] + atomicAdd(&cur[b], 1);
        if (r < CAP) staged[(size_t)b * CAP + r] = (u32)s | ((u32)dl << 17);
    }
}

// ---------------- pass B: per-bucket CSR build entirely in LDS ----------------
// outputs: csr (src ids PRE-SCALED by 8 = uint4-row units), meta[n], dinv[n]

__global__ __launch_bounds__(256) void k_csr(const int* __restrict__ gcur,
                                             const u32* __restrict__ staged,
                                             int* __restrict__ csr,
                                             int4* __restrict__ meta,
                                             float* __restrict__ dinv) {
    __shared__ u32 sedge[CAP];   // 32 KB
    __shared__ int lcsr[CAP];    // 32 KB
    __shared__ int hist[BN];
    __shared__ int lrs[BN];
    __shared__ int cur[BN];
    __shared__ int sbuf[256];
    int b = blockIdx.x, t = threadIdx.x;

    // bucket base = sum of clamped counts of buckets < b (block reduce)
    int part = 0;
    for (int i = t; i < b; i += 256) {
        int c = gcur[i]; if (c > CAP) c = CAP;
        part += c;
    }
    sbuf[t] = part;
    __syncthreads();
    for (int off = 128; off; off >>= 1) {
        if (t < off) sbuf[t] += sbuf[t + off];
        __syncthreads();
    }
    int base_ = sbuf[0];
    __syncthreads();

    int cnt = gcur[b]; if (cnt > CAP) cnt = CAP;
    for (int i = t; i < BN; i += 256) hist[i] = 0;
    for (int i = t; i < cnt; i += 256) sedge[i] = staged[(size_t)b * CAP + i];
    __syncthreads();
    for (int i = t; i < cnt; i += 256) atomicAdd(&hist[sedge[i] >> 17], 1);
    __syncthreads();

    // exclusive scan of hist[0..BN) (2 elems/thread)
    int v0 = (2 * t < BN) ? hist[2 * t] : 0;
    int v1 = (2 * t + 1 < BN) ? hist[2 * t + 1] : 0;
    int s = v0 + v1;
    sbuf[t] = s;
    __syncthreads();
    for (int off = 1; off < 256; off <<= 1) {
        int add = (t >= off) ? sbuf[t - off] : 0;
        __syncthreads();
        sbuf[t] += add;
        __syncthreads();
    }
    int excl = sbuf[t] - s;
    if (2 * t < BN)     { lrs[2 * t] = excl;      cur[2 * t] = excl; }
    if (2 * t + 1 < BN) { lrs[2 * t + 1] = excl + v0; cur[2 * t + 1] = excl + v0; }
    __syncthreads();

    // fill local CSR (random writes stay in LDS); store src*8 (uint4-row units)
    for (int i = t; i < cnt; i += 256) {
        u32 p = sedge[i];
        int pos = atomicAdd(&cur[p >> 17], 1);
        lcsr[pos] = (int)((p & 0x1FFFF) << 3);
    }
    __syncthreads();

    // coalesced writeout
    for (int i = t; i < cnt; i += 256) csr[base_ + i] = lcsr[i];
    int n0 = b * BN;
    for (int i = t; i < BN; i += 256) {
        int n = n0 + i;
        if (n < N_NODES) {
            int dg = hist[i];
            float dv = rsqrtf((float)dg + 1.0f);
            meta[n] = make_int4(base_ + lrs[i], dg, __float_as_int(dv), 0);
            dinv[n] = dv;
        }
    }
}

// ---------------- GEMM1: h1s = f16((x @ W1) * dinv[row])  [N,64] ----------------

__global__ __launch_bounds__(256) void k_gemm1(const float* __restrict__ x,
                                               const float* __restrict__ W1,
                                               const float* __restrict__ dinv,
                                               u16* __restrict__ h1s) {
    __shared__ float xs[64 * 140];     // 35 KB
    __shared__ float wsh[DIN * DH];    // 32 KB
    int t = threadIdx.x;
    int row0 = blockIdx.x * 64;

    for (int it = 0; it < 8; ++it) {
        int idx = (it * 256 + t) * 4;
        int r = idx >> 7, c = idx & 127;
        float4 v = make_float4(0.f, 0.f, 0.f, 0.f);
        if (row0 + r < N_NODES) v = *(const float4*)&x[(size_t)(row0 + r) * DIN + c];
        *(float4*)&xs[r * 140 + c] = v;
    }
    for (int it = 0; it < 8; ++it) {
        int idx = (it * 256 + t) * 4;
        *(float4*)&wsh[idx] = *(const float4*)&W1[idx];
    }
    __syncthreads();

    int tr = t & 15;   // feature group: features tr*4..tr*4+3
    int tc = t >> 4;   // row group: rows tc*4..tc*4+3
    float acc[4][4] = {};
    for (int kb = 0; kb < DIN; kb += 4) {
        float4 w0 = *(const float4*)&wsh[(kb + 0) * DH + tr * 4];
        float4 w1 = *(const float4*)&wsh[(kb + 1) * DH + tr * 4];
        float4 w2 = *(const float4*)&wsh[(kb + 2) * DH + tr * 4];
        float4 w3 = *(const float4*)&wsh[(kb + 3) * DH + tr * 4];
#pragma unroll
        for (int i = 0; i < 4; ++i) {
            float4 xv = *(const float4*)&xs[(tc * 4 + i) * 140 + kb];
            acc[i][0] += xv.x * w0.x; acc[i][1] += xv.x * w0.y;
            acc[i][2] += xv.x * w0.z; acc[i][3] += xv.x * w0.w;
            acc[i][0] += xv.y * w1.x; acc[i][1] += xv.y * w1.y;
            acc[i][2] += xv.y * w1.z; acc[i][3] += xv.y * w1.w;
            acc[i][0] += xv.z * w2.x; acc[i][1] += xv.z * w2.y;
            acc[i][2] += xv.z * w2.z; acc[i][3] += xv.z * w2.w;
            acc[i][0] += xv.w * w3.x; acc[i][1] += xv.w * w3.y;
            acc[i][2] += xv.w * w3.z; acc[i][3] += xv.w * w3.w;
        }
    }
#pragma unroll
    for (int i = 0; i < 4; ++i) {
        int row = row0 + tc * 4 + i;
        if (row < N_NODES) {
            float dv = dinv[row];
            ushort4 o;
            o.x = __half_as_ushort(__float2half(acc[i][0] * dv));
            o.y = __half_as_ushort(__float2half(acc[i][1] * dv));
            o.z = __half_as_ushort(__float2half(acc[i][2] * dv));
            o.w = __half_as_ushort(__float2half(acc[i][3] * dv));
            *(ushort4*)&h1s[(size_t)row * DH + tr * 4] = o;
        }
    }
}

// ---------------- agg1 (pull): h1 = relu(dinv*(sum h1s[src] + h1s[n]) + b1) ----------------
// one wave per node; lane = (edge-slot es 0..7, feature-quad fq 0..7); 16 B/lane
// gathers (uint4). CSR entries pre-scaled by 8 -> address is x + fq.

__global__ __launch_bounds__(256) void k_agg1(const u16* __restrict__ h1s,
                                              const int4* __restrict__ meta,
                                              const int* __restrict__ csr,
                                              const float* __restrict__ b1,
                                              float* __restrict__ h1) {
    int node = blockIdx.x * 4 + (threadIdx.x >> 6);
    if (node >= N_NODES) return;
    node = __builtin_amdgcn_readfirstlane(node);
    int lane = threadIdx.x & 63;
    int es = lane >> 3, fq = lane & 7;
    int4 me = meta[node];
    int s0 = me.x, d = me.y;
    float dv = __int_as_float(me.z);
    const uint4* rows = (const uint4*)h1s;  // row stride = 8 uint4 (128 B)
    __half2 A0 = __float2half2_rn(0.f), A1 = A0, A2 = A0, A3 = A0;
    if (es == 0) {
        uint4 v = rows[(u32)(node * 8 + fq)];  // self
        A0 = u2h(v.x); A1 = u2h(v.y); A2 = u2h(v.z); A3 = u2h(v.w);
    }
    for (int base = 0; base < d; base += 64) {
        int nn = d - base; if (nn > 64) nn = 64;
        int myidx = (lane < nn) ? csr[s0 + base + lane] : 0;
        int j = 0;
        for (; j + 16 <= nn; j += 16) {
            int x0 = __builtin_amdgcn_ds_bpermute((j + es) * 4, myidx);
            int x1 = __builtin_amdgcn_ds_bpermute((j + 8 + es) * 4, myidx);
            uint4 v0 = rows[(u32)(x0 + fq)];
            uint4 v1 = rows[(u32)(x1 + fq)];
            A0 = __hadd2(A0, u2h(v0.x)); A1 = __hadd2(A1, u2h(v0.y));
            A2 = __hadd2(A2, u2h(v0.z)); A3 = __hadd2(A3, u2h(v0.w));
            A0 = __hadd2(A0, u2h(v1.x)); A1 = __hadd2(A1, u2h(v1.y));
            A2 = __hadd2(A2, u2h(v1.z)); A3 = __hadd2(A3, u2h(v1.w));
        }
        for (; j < nn; j += 8) {
            int x = __builtin_amdgcn_ds_bpermute((j + es) * 4, myidx);
            if (j + es < nn) {
                uint4 v = rows[(u32)(x + fq)];
                A0 = __hadd2(A0, u2h(v.x)); A1 = __hadd2(A1, u2h(v.y));
                A2 = __hadd2(A2, u2h(v.z)); A3 = __hadd2(A3, u2h(v.w));
            }
        }
    }
    // butterfly-reduce across the 8 edge slots (xor 8,16,32)
#pragma unroll
    for (int off = 8; off <= 32; off <<= 1) {
        A0 = __hadd2(A0, u2h((u32)__shfl_xor((int)h2u(A0), off, 64)));
        A1 = __hadd2(A1, u2h((u32)__shfl_xor((int)h2u(A1), off, 64)));
        A2 = __hadd2(A2, u2h((u32)__shfl_xor((int)h2u(A2), off, 64)));
        A3 = __hadd2(A3, u2h((u32)__shfl_xor((int)h2u(A3), off, 64)));
    }
    if (es == 0) {
        float4 bva = ((const float4*)b1)[fq * 2 + 0];
        float4 bvb = ((const float4*)b1)[fq * 2 + 1];
        float4 oa, ob;
        oa.x = fmaxf(__low2float(A0)  * dv + bva.x, 0.f);
        oa.y = fmaxf(__high2float(A0) * dv + bva.y, 0.f);
        oa.z = fmaxf(__low2float(A1)  * dv + bva.z, 0.f);
        oa.w = fmaxf(__high2float(A1) * dv + bva.w, 0.f);
        ob.x = fmaxf(__low2float(A2)  * dv + bvb.x, 0.f);
        ob.y = fmaxf(__high2float(A2) * dv + bvb.y, 0.f);
        ob.z = fmaxf(__low2float(A3)  * dv + bvb.z, 0.f);
        ob.w = fmaxf(__high2float(A3) * dv + bvb.w, 0.f);
        ((float4*)h1)[(u32)(node * 16 + fq * 2 + 0)] = oa;
        ((float4*)h1)[(u32)(node * 16 + fq * 2 + 1)] = ob;
    }
}

// ---------------- GEMM2: h2s = f16((h1 @ W2) * dinv[row])  [N,64-padded] ----------------
// pad (features 40..63) never read by agg2 (exec-masked) -> no zeroing needed.

__global__ __launch_bounds__(256) void k_gemm2(const float* __restrict__ h1,
                                               const float* __restrict__ W2,
                                               const float* __restrict__ dinv,
                                               u16* __restrict__ h2s) {
    __shared__ float xs[64 * 68];
    __shared__ float wsh[DH * DOUT];
    int t = threadIdx.x;
    int row0 = blockIdx.x * 64;

    for (int it = 0; it < 4; ++it) {
        int idx = (it * 256 + t) * 4;
        int r = idx >> 6, c = idx & 63;
        float4 v = make_float4(0.f, 0.f, 0.f, 0.f);
        if (row0 + r < N_NODES) v = *(const float4*)&h1[(size_t)(row0 + r) * DH + c];
        *(float4*)&xs[r * 68 + c] = v;
    }
    for (int idx = t * 4; idx < DH * DOUT; idx += 1024) {
        *(float4*)&wsh[idx] = *(const float4*)&W2[idx];
    }
    __syncthreads();

    int fg = t & 7;
    int rg = t >> 3;
    float acc[2][5] = {};
    for (int k = 0; k < DH; ++k) {
        float x0 = xs[(rg * 2 + 0) * 68 + k];
        float x1 = xs[(rg * 2 + 1) * 68 + k];
#pragma unroll
        for (int j = 0; j < 5; ++j) {
            float w = wsh[k * DOUT + fg * 5 + j];
            acc[0][j] += x0 * w;
            acc[1][j] += x1 * w;
        }
    }
#pragma unroll
    for (int i = 0; i < 2; ++i) {
        int row = row0 + rg * 2 + i;
        if (row < N_NODES) {
            float dvv = dinv[row];
#pragma unroll
            for (int j = 0; j < 5; ++j)
                h2s[(size_t)row * 64 + fg * 5 + j] =
                    __half_as_ushort(__float2half(acc[i][j] * dvv));
        }
    }
}

// ---------------- agg2 (pull) + bias + log_softmax ----------------
// 8-slot uint4 layout on padded rows; ONLY fq<5 lanes issue gathers.
// Fast __expf/__logf in the softmax epilogue.

__global__ __launch_bounds__(256) void k_agg2(const u16* __restrict__ h2s,
                                              const int4* __restrict__ meta,
                                              const int* __restrict__ csr,
                                              const float* __restrict__ b2,
                                              float* __restrict__ out) {
    int node = blockIdx.x * 4 + (threadIdx.x >> 6);
    if (node >= N_NODES) return;
    node = __builtin_amdgcn_readfirstlane(node);
    int lane = threadIdx.x & 63;
    int es = lane >> 3, fq = lane & 7;
    bool act = fq < 5;
    int4 me = meta[node];
    int s0 = me.x, d = me.y;
    float dv = __int_as_float(me.z);
    const uint4* rows = (const uint4*)h2s;  // padded row stride = 8 uint4
    __half2 A0 = __float2half2_rn(0.f), A1 = A0, A2 = A0, A3 = A0;
    if (es == 0 && act) {
        uint4 v = rows[(u32)(node * 8 + fq)];  // self
        A0 = u2h(v.x); A1 = u2h(v.y); A2 = u2h(v.z); A3 = u2h(v.w);
    }
    for (int base = 0; base < d; base += 64) {
        int nn = d - base; if (nn > 64) nn = 64;
        int myidx = (lane < nn) ? csr[s0 + base + lane] : 0;
        int j = 0;
        for (; j + 16 <= nn; j += 16) {
            int x0 = __builtin_amdgcn_ds_bpermute((j + es) * 4, myidx);
            int x1 = __builtin_amdgcn_ds_bpermute((j + 8 + es) * 4, myidx);
            if (act) {
                uint4 v0 = rows[(u32)(x0 + fq)];
                uint4 v1 = rows[(u32)(x1 + fq)];
                A0 = __hadd2(A0, u2h(v0.x)); A1 = __hadd2(A1, u2h(v0.y));
                A2 = __hadd2(A2, u2h(v0.z)); A3 = __hadd2(A3, u2h(v0.w));
                A0 = __hadd2(A0, u2h(v1.x)); A1 = __hadd2(A1, u2h(v1.y));
                A2 = __hadd2(A2, u2h(v1.z)); A3 = __hadd2(A3, u2h(v1.w));
            }
        }
        for (; j < nn; j += 8) {
            int x = __builtin_amdgcn_ds_bpermute((j + es) * 4, myidx);
            if (act && j + es < nn) {
                uint4 v = rows[(u32)(x + fq)];
                A0 = __hadd2(A0, u2h(v.x)); A1 = __hadd2(A1, u2h(v.y));
                A2 = __hadd2(A2, u2h(v.z)); A3 = __hadd2(A3, u2h(v.w));
            }
        }
    }
    // butterfly-reduce across the 8 edge slots
#pragma unroll
    for (int off = 8; off <= 32; off <<= 1) {
        A0 = __hadd2(A0, u2h((u32)__shfl_xor((int)h2u(A0), off, 64)));
        A1 = __hadd2(A1, u2h((u32)__shfl_xor((int)h2u(A1), off, 64)));
        A2 = __hadd2(A2, u2h((u32)__shfl_xor((int)h2u(A2), off, 64)));
        A3 = __hadd2(A3, u2h((u32)__shfl_xor((int)h2u(A3), off, 64)));
    }

    // bias + log_softmax over 40 features (5 fq groups x 8)
    float4 bva = act ? ((const float4*)b2)[fq * 2 + 0] : make_float4(0.f, 0.f, 0.f, 0.f);
    float4 bvb = act ? ((const float4*)b2)[fq * 2 + 1] : make_float4(0.f, 0.f, 0.f, 0.f);
    float v0 = act ? __low2float(A0)  * dv + bva.x : -INFINITY;
    float v1 = act ? __high2float(A0) * dv + bva.y : -INFINITY;
    float v2 = act ? __low2float(A1)  * dv + bva.z : -INFINITY;
    float v3 = act ? __high2float(A1) * dv + bva.w : -INFINITY;
    float v4 = act ? __low2float(A2)  * dv + bvb.x : -INFINITY;
    float v5 = act ? __high2float(A2) * dv + bvb.y : -INFINITY;
    float v6 = act ? __low2float(A3)  * dv + bvb.z : -INFINITY;
    float v7 = act ? __high2float(A3) * dv + bvb.w : -INFINITY;
    float m = fmaxf(fmaxf(fmaxf(v0, v1), fmaxf(v2, v3)),
                    fmaxf(fmaxf(v4, v5), fmaxf(v6, v7)));
    m = fmaxf(m, __shfl_xor(m, 1, 64));
    m = fmaxf(m, __shfl_xor(m, 2, 64));
    m = fmaxf(m, __shfl_xor(m, 4, 64));
    float ex = 0.f;
    if (act) {
        ex = __expf(v0 - m) + __expf(v1 - m) + __expf(v2 - m) + __expf(v3 - m)
           + __expf(v4 - m) + __expf(v5 - m) + __expf(v6 - m) + __expf(v7 - m);
    }
    ex += __shfl_xor(ex, 1, 64);
    ex += __shfl_xor(ex, 2, 64);
    ex += __shfl_xor(ex, 4, 64);
    float lse = m + __logf(ex);
    if (es == 0 && act) {
        float4 oa = make_float4(v0 - lse, v1 - lse, v2 - lse, v3 - lse);
        float4 ob = make_float4(v4 - lse, v5 - lse, v6 - lse, v7 - lse);
        *(float4*)&out[(u32)(node * 40 + fq * 8 + 0)] = oa;
        *(float4*)&out[(u32)(node * 40 + fq * 8 + 4)] = ob;
    }
}

// ---------------- launch ----------------

extern "C" void kernel_launch(void* const* d_in, const int* in_sizes, int n_in,
                              void* d_out, int out_size, void* d_ws, size_t ws_size,
                              hipStream_t stream) {
    const float* x  = (const float*)d_in[0];
    const float* W1 = (const float*)d_in[1];
    const float* b1 = (const float*)d_in[2];
    const float* W2 = (const float*)d_in[3];
    const float* b2 = (const float*)d_in[4];
    const int* eidx = (const int*)d_in[5];
    const int* srcp = eidx;
    const int* dstp = eidx + N_EDGES;
    float* out = (float*)d_out;

    char* w = (char*)d_ws;
    int* gcur    = (int*)w;   w += sizeof(int) * NB;
    float* dinv  = (float*)w; w += sizeof(float) * N_NODES + 48;  // keep int4 alignment
    int4* meta   = (int4*)w;  w += sizeof(int4) * N_NODES;
    u32* staged  = (u32*)w;   w += sizeof(u32) * (size_t)NB * CAP;       // 8 MB
    int* csr     = (int*)w;   w += sizeof(int) * N_EDGES;                // 6.4 MB
    u16* h1s     = (u16*)w;   w += sizeof(u16) * (size_t)N_NODES * DH;   // f16 [N,64]
    float* h1    = (float*)w; w += sizeof(float) * (size_t)N_NODES * DH; // f32 [N,64]
    u16* h2s     = h1s;  // alias: h1s dead after agg1; h2s is f16 [N,64-padded]

    hipMemsetAsync(gcur, 0, sizeof(int) * NB, stream);
    k_bin<<<BIN_BLOCKS, 1024, 0, stream>>>(srcp, dstp, gcur, staged);
    k_csr<<<NB, 256, 0, stream>>>(gcur, staged, csr, meta, dinv);
    k_gemm1<<<(N_NODES + 63) / 64, 256, 0, stream>>>(x, W1, dinv, h1s);
    k_agg1<<<(N_NODES + 3) / 4, 256, 0, stream>>>(h1s, meta, csr, b1, h1);
    k_gemm2<<<(N_NODES + 63) / 64, 256, 0, stream>>>(h1, W2, dinv, h2s);
    k_agg2<<<(N_NODES + 3) / 4, 256, 0, stream>>>(h2s, meta, csr, b2, out);
}

// Round 14
// 202.000 us; speedup vs baseline: 1.3870x; 1.0048x over previous
//
#include <hip/hip_runtime.h>
#include <hip/hip_fp16.h>
#include <math.h>

#define N_NODES 100000
#define N_EDGES 1600000
#define DIN 128
#define DH 64
#define DOUT 40

#define NB 256        // dst buckets
#define BN 391        // nodes per bucket (256*391 = 100096 >= 100000)
#define CAP 8192      // staged capacity per bucket (mean 6250, sd ~79)
#define BIN_BLOCKS 256
#define EPB 6250      // edges per k_bin block (256*6250 = 1.6M)

typedef unsigned short u16;
typedef unsigned int u32;

__device__ inline __half2 u2h(u32 u) {
    union { u32 x; __half2 h; } c; c.x = u; return c.h;
}
__device__ inline u32 h2u(__half2 h) {
    union { __half2 h; u32 x; } c; c.h = h; return c.x;
}

// ---------------- pass A: bin edges by dst bucket ----------------
// staged entry: src (17 bits) | dstlocal (9 bits) << 17
// 1024 threads/block: latency-bound scatter at 1 block/CU needs wide blocks
// for TLP. Scatter uses REGULAR stores (L2 write-combining; nt-scatter = 16x
// write amplification, R11).

__global__ __launch_bounds__(1024) void k_bin(const int* __restrict__ src,
                                              const int* __restrict__ dst,
                                              int* __restrict__ gcur,
                                              u32* __restrict__ staged) {
    __shared__ int hist[NB];
    __shared__ int base[NB];
    __shared__ int cur[NB];
    int t = threadIdx.x;
    for (int i = t; i < NB; i += 1024) { hist[i] = 0; cur[i] = 0; }
    __syncthreads();
    int e0 = blockIdx.x * EPB;
    int e1 = e0 + EPB; if (e1 > N_EDGES) e1 = N_EDGES;
    for (int e = e0 + t; e < e1; e += 1024)
        atomicAdd(&hist[dst[e] / BN], 1);
    __syncthreads();
    for (int i = t; i < NB; i += 1024) {
        int h = hist[i];
        base[i] = h ? atomicAdd(&gcur[i], h) : 0;
    }
    __syncthreads();
    for (int e = e0 + t; e < e1; e += 1024) {
        int d = dst[e], s = src[e];
        int b = d / BN;
        int dl = d - b * BN;
        int r = base[b] + atomicAdd(&cur[b], 1);
        if (r < CAP) staged[(size_t)b * CAP + r] = (u32)s | ((u32)dl << 17);
    }
}

// ---------------- pass B: per-bucket CSR build entirely in LDS ----------------
// outputs: csr (RAW src ids), meta[n] = {rowstart, deg, dinv_bits, 0}, dinv[n]

__global__ __launch_bounds__(256) void k_csr(const int* __restrict__ gcur,
                                             const u32* __restrict__ staged,
                                             int* __restrict__ csr,
                                             int4* __restrict__ meta,
                                             float* __restrict__ dinv) {
    __shared__ u32 sedge[CAP];   // 32 KB
    __shared__ int lcsr[CAP];    // 32 KB
    __shared__ int hist[BN];
    __shared__ int lrs[BN];
    __shared__ int cur[BN];
    __shared__ int sbuf[256];
    int b = blockIdx.x, t = threadIdx.x;

    // bucket base = sum of clamped counts of buckets < b (block reduce)
    int part = 0;
    for (int i = t; i < b; i += 256) {
        int c = gcur[i]; if (c > CAP) c = CAP;
        part += c;
    }
    sbuf[t] = part;
    __syncthreads();
    for (int off = 128; off; off >>= 1) {
        if (t < off) sbuf[t] += sbuf[t + off];
        __syncthreads();
    }
    int base_ = sbuf[0];
    __syncthreads();

    int cnt = gcur[b]; if (cnt > CAP) cnt = CAP;
    for (int i = t; i < BN; i += 256) hist[i] = 0;
    for (int i = t; i < cnt; i += 256) sedge[i] = staged[(size_t)b * CAP + i];
    __syncthreads();
    for (int i = t; i < cnt; i += 256) atomicAdd(&hist[sedge[i] >> 17], 1);
    __syncthreads();

    // exclusive scan of hist[0..BN) (2 elems/thread)
    int v0 = (2 * t < BN) ? hist[2 * t] : 0;
    int v1 = (2 * t + 1 < BN) ? hist[2 * t + 1] : 0;
    int s = v0 + v1;
    sbuf[t] = s;
    __syncthreads();
    for (int off = 1; off < 256; off <<= 1) {
        int add = (t >= off) ? sbuf[t - off] : 0;
        __syncthreads();
        sbuf[t] += add;
        __syncthreads();
    }
    int excl = sbuf[t] - s;
    if (2 * t < BN)     { lrs[2 * t] = excl;      cur[2 * t] = excl; }
    if (2 * t + 1 < BN) { lrs[2 * t + 1] = excl + v0; cur[2 * t + 1] = excl + v0; }
    __syncthreads();

    // fill local CSR (random writes stay in LDS); store RAW src id
    for (int i = t; i < cnt; i += 256) {
        u32 p = sedge[i];
        int pos = atomicAdd(&cur[p >> 17], 1);
        lcsr[pos] = (int)(p & 0x1FFFF);
    }
    __syncthreads();

    // coalesced writeout
    for (int i = t; i < cnt; i += 256) csr[base_ + i] = lcsr[i];
    int n0 = b * BN;
    for (int i = t; i < BN; i += 256) {
        int n = n0 + i;
        if (n < N_NODES) {
            int dg = hist[i];
            float dv = rsqrtf((float)dg + 1.0f);
            meta[n] = make_int4(base_ + lrs[i], dg, __float_as_int(dv), 0);
            dinv[n] = dv;
        }
    }
}

// ---------------- GEMM1: h1s = f16((x @ W1) * dinv[row])  [N,64] ----------------

__global__ __launch_bounds__(256) void k_gemm1(const float* __restrict__ x,
                                               const float* __restrict__ W1,
                                               const float* __restrict__ dinv,
                                               u16* __restrict__ h1s) {
    __shared__ float xs[64 * 140];     // 35 KB
    __shared__ float wsh[DIN * DH];    // 32 KB
    int t = threadIdx.x;
    int row0 = blockIdx.x * 64;

    for (int it = 0; it < 8; ++it) {
        int idx = (it * 256 + t) * 4;
        int r = idx >> 7, c = idx & 127;
        float4 v = make_float4(0.f, 0.f, 0.f, 0.f);
        if (row0 + r < N_NODES) v = *(const float4*)&x[(size_t)(row0 + r) * DIN + c];
        *(float4*)&xs[r * 140 + c] = v;
    }
    for (int it = 0; it < 8; ++it) {
        int idx = (it * 256 + t) * 4;
        *(float4*)&wsh[idx] = *(const float4*)&W1[idx];
    }
    __syncthreads();

    int tr = t & 15;   // feature group: features tr*4..tr*4+3
    int tc = t >> 4;   // row group: rows tc*4..tc*4+3
    float acc[4][4] = {};
    for (int kb = 0; kb < DIN; kb += 4) {
        float4 w0 = *(const float4*)&wsh[(kb + 0) * DH + tr * 4];
        float4 w1 = *(const float4*)&wsh[(kb + 1) * DH + tr * 4];
        float4 w2 = *(const float4*)&wsh[(kb + 2) * DH + tr * 4];
        float4 w3 = *(const float4*)&wsh[(kb + 3) * DH + tr * 4];
#pragma unroll
        for (int i = 0; i < 4; ++i) {
            float4 xv = *(const float4*)&xs[(tc * 4 + i) * 140 + kb];
            acc[i][0] += xv.x * w0.x; acc[i][1] += xv.x * w0.y;
            acc[i][2] += xv.x * w0.z; acc[i][3] += xv.x * w0.w;
            acc[i][0] += xv.y * w1.x; acc[i][1] += xv.y * w1.y;
            acc[i][2] += xv.y * w1.z; acc[i][3] += xv.y * w1.w;
            acc[i][0] += xv.z * w2.x; acc[i][1] += xv.z * w2.y;
            acc[i][2] += xv.z * w2.z; acc[i][3] += xv.z * w2.w;
            acc[i][0] += xv.w * w3.x; acc[i][1] += xv.w * w3.y;
            acc[i][2] += xv.w * w3.z; acc[i][3] += xv.w * w3.w;
        }
    }
#pragma unroll
    for (int i = 0; i < 4; ++i) {
        int row = row0 + tc * 4 + i;
        if (row < N_NODES) {
            float dv = dinv[row];
            ushort4 o;
            o.x = __half_as_ushort(__float2half(acc[i][0] * dv));
            o.y = __half_as_ushort(__float2half(acc[i][1] * dv));
            o.z = __half_as_ushort(__float2half(acc[i][2] * dv));
            o.w = __half_as_ushort(__float2half(acc[i][3] * dv));
            *(ushort4*)&h1s[(size_t)row * DH + tr * 4] = o;
        }
    }
}

// ---------------- agg1 (pull): h1f = f16(relu(dinv*(sum h1s[src] + h1s[n]) + b1)) ----
// one wave per node; lane = (edge-slot es 0..7, feature-quad fq 0..7); 16 B/lane
// gathers (uint4). CSR raw idx -> address = idx*8 + fq (v_lshl_add).
// Output h1f f16 [N,64] -> halves the write + gemm2's read.

__global__ __launch_bounds__(256) void k_agg1(const u16* __restrict__ h1s,
                                              const int4* __restrict__ meta,
                                              const int* __restrict__ csr,
                                              const float* __restrict__ b1,
                                              u16* __restrict__ h1f) {
    int node = blockIdx.x * 4 + (threadIdx.x >> 6);
    if (node >= N_NODES) return;
    node = __builtin_amdgcn_readfirstlane(node);
    int lane = threadIdx.x & 63;
    int es = lane >> 3, fq = lane & 7;
    int4 me = meta[node];
    int s0 = me.x, d = me.y;
    float dv = __int_as_float(me.z);
    const uint4* rows = (const uint4*)h1s;  // row stride = 8 uint4 (128 B)
    __half2 A0 = __float2half2_rn(0.f), A1 = A0, A2 = A0, A3 = A0;
    if (es == 0) {
        uint4 v = rows[(u32)(node * 8 + fq)];  // self
        A0 = u2h(v.x); A1 = u2h(v.y); A2 = u2h(v.z); A3 = u2h(v.w);
    }
    for (int base = 0; base < d; base += 64) {
        int nn = d - base; if (nn > 64) nn = 64;
        int myidx = (lane < nn) ? csr[s0 + base + lane] : 0;
        int j = 0;
        for (; j + 16 <= nn; j += 16) {
            int x0 = __builtin_amdgcn_ds_bpermute((j + es) * 4, myidx);
            int x1 = __builtin_amdgcn_ds_bpermute((j + 8 + es) * 4, myidx);
            uint4 v0 = rows[(u32)(x0 * 8 + fq)];
            uint4 v1 = rows[(u32)(x1 * 8 + fq)];
            A0 = __hadd2(A0, u2h(v0.x)); A1 = __hadd2(A1, u2h(v0.y));
            A2 = __hadd2(A2, u2h(v0.z)); A3 = __hadd2(A3, u2h(v0.w));
            A0 = __hadd2(A0, u2h(v1.x)); A1 = __hadd2(A1, u2h(v1.y));
            A2 = __hadd2(A2, u2h(v1.z)); A3 = __hadd2(A3, u2h(v1.w));
        }
        for (; j < nn; j += 8) {
            int x = __builtin_amdgcn_ds_bpermute((j + es) * 4, myidx);
            if (j + es < nn) {
                uint4 v = rows[(u32)(x * 8 + fq)];
                A0 = __hadd2(A0, u2h(v.x)); A1 = __hadd2(A1, u2h(v.y));
                A2 = __hadd2(A2, u2h(v.z)); A3 = __hadd2(A3, u2h(v.w));
            }
        }
    }
    // butterfly-reduce across the 8 edge slots (xor 8,16,32)
#pragma unroll
    for (int off = 8; off <= 32; off <<= 1) {
        A0 = __hadd2(A0, u2h((u32)__shfl_xor((int)h2u(A0), off, 64)));
        A1 = __hadd2(A1, u2h((u32)__shfl_xor((int)h2u(A1), off, 64)));
        A2 = __hadd2(A2, u2h((u32)__shfl_xor((int)h2u(A2), off, 64)));
        A3 = __hadd2(A3, u2h((u32)__shfl_xor((int)h2u(A3), off, 64)));
    }
    if (es == 0) {
        float4 bva = ((const float4*)b1)[fq * 2 + 0];
        float4 bvb = ((const float4*)b1)[fq * 2 + 1];
        float f0 = fmaxf(__low2float(A0)  * dv + bva.x, 0.f);
        float f1 = fmaxf(__high2float(A0) * dv + bva.y, 0.f);
        float f2 = fmaxf(__low2float(A1)  * dv + bva.z, 0.f);
        float f3 = fmaxf(__high2float(A1) * dv + bva.w, 0.f);
        float f4 = fmaxf(__low2float(A2)  * dv + bvb.x, 0.f);
        float f5 = fmaxf(__high2float(A2) * dv + bvb.y, 0.f);
        float f6 = fmaxf(__low2float(A3)  * dv + bvb.z, 0.f);
        float f7 = fmaxf(__high2float(A3) * dv + bvb.w, 0.f);
        uint4 ov;
        ov.x = h2u(__floats2half2_rn(f0, f1));
        ov.y = h2u(__floats2half2_rn(f2, f3));
        ov.z = h2u(__floats2half2_rn(f4, f5));
        ov.w = h2u(__floats2half2_rn(f6, f7));
        ((uint4*)h1f)[(u32)(node * 8 + fq)] = ov;
    }
}

// ---------------- GEMM2: h2s = f16((h1f @ W2) * dinv[row])  [N,40] compact ----------------
// h1f is f16: stage with cvt; h2s rows are 80 B (5 uint4, 16B-aligned).

__global__ __launch_bounds__(256) void k_gemm2(const u16* __restrict__ h1f,
                                               const float* __restrict__ W2,
                                               const float* __restrict__ dinv,
                                               u16* __restrict__ h2s) {
    __shared__ float xs[64 * 68];
    __shared__ float wsh[DH * DOUT];
    int t = threadIdx.x;
    int row0 = blockIdx.x * 64;

    for (int it = 0; it < 4; ++it) {   // 64x64 f16 = 4096 vals, 4 per thread-iter
        int idx = (it * 256 + t) * 4;
        int r = idx >> 6, c = idx & 63;
        float4 v = make_float4(0.f, 0.f, 0.f, 0.f);
        if (row0 + r < N_NODES) {
            uint2 hv = *(const uint2*)&h1f[(size_t)(row0 + r) * DH + c];
            __half2 hlo = u2h(hv.x), hhi = u2h(hv.y);
            v = make_float4(__low2float(hlo), __high2float(hlo),
                            __low2float(hhi), __high2float(hhi));
        }
        *(float4*)&xs[r * 68 + c] = v;
    }
    for (int idx = t * 4; idx < DH * DOUT; idx += 1024) {
        *(float4*)&wsh[idx] = *(const float4*)&W2[idx];
    }
    __syncthreads();

    int fg = t & 7;
    int rg = t >> 3;
    float acc[2][5] = {};
    for (int k = 0; k < DH; ++k) {
        float x0 = xs[(rg * 2 + 0) * 68 + k];
        float x1 = xs[(rg * 2 + 1) * 68 + k];
#pragma unroll
        for (int j = 0; j < 5; ++j) {
            float w = wsh[k * DOUT + fg * 5 + j];
            acc[0][j] += x0 * w;
            acc[1][j] += x1 * w;
        }
    }
#pragma unroll
    for (int i = 0; i < 2; ++i) {
        int row = row0 + rg * 2 + i;
        if (row < N_NODES) {
            float dvv = dinv[row];
#pragma unroll
            for (int j = 0; j < 5; ++j)
                h2s[(size_t)row * DOUT + fg * 5 + j] =
                    __half_as_ushort(__float2half(acc[i][j] * dvv));
        }
    }
}

// ---------------- agg2 (pull) + bias + log_softmax ----------------
// compact [N,40] rows (5 uint4); fq<5 lanes gather; addr = idx*5 + fq.
// Fast __expf/__logf in the softmax epilogue.

__global__ __launch_bounds__(256) void k_agg2(const u16* __restrict__ h2s,
                                              const int4* __restrict__ meta,
                                              const int* __restrict__ csr,
                                              const float* __restrict__ b2,
                                              float* __restrict__ out) {
    int node = blockIdx.x * 4 + (threadIdx.x >> 6);
    if (node >= N_NODES) return;
    node = __builtin_amdgcn_readfirstlane(node);
    int lane = threadIdx.x & 63;
    int es = lane >> 3, fq = lane & 7;
    bool act = fq < 5;
    int4 me = meta[node];
    int s0 = me.x, d = me.y;
    float dv = __int_as_float(me.z);
    const uint4* rows = (const uint4*)h2s;  // row stride = 5 uint4 (80 B)
    __half2 A0 = __float2half2_rn(0.f), A1 = A0, A2 = A0, A3 = A0;
    if (es == 0 && act) {
        uint4 v = rows[(u32)(node * 5 + fq)];  // self
        A0 = u2h(v.x); A1 = u2h(v.y); A2 = u2h(v.z); A3 = u2h(v.w);
    }
    for (int base = 0; base < d; base += 64) {
        int nn = d - base; if (nn > 64) nn = 64;
        int myidx = (lane < nn) ? csr[s0 + base + lane] : 0;
        int j = 0;
        for (; j + 16 <= nn; j += 16) {
            int x0 = __builtin_amdgcn_ds_bpermute((j + es) * 4, myidx);
            int x1 = __builtin_amdgcn_ds_bpermute((j + 8 + es) * 4, myidx);
            if (act) {
                uint4 v0 = rows[(u32)(x0 * 5 + fq)];
                uint4 v1 = rows[(u32)(x1 * 5 + fq)];
                A0 = __hadd2(A0, u2h(v0.x)); A1 = __hadd2(A1, u2h(v0.y));
                A2 = __hadd2(A2, u2h(v0.z)); A3 = __hadd2(A3, u2h(v0.w));
                A0 = __hadd2(A0, u2h(v1.x)); A1 = __hadd2(A1, u2h(v1.y));
                A2 = __hadd2(A2, u2h(v1.z)); A3 = __hadd2(A3, u2h(v1.w));
            }
        }
        for (; j < nn; j += 8) {
            int x = __builtin_amdgcn_ds_bpermute((j + es) * 4, myidx);
            if (act && j + es < nn) {
                uint4 v = rows[(u32)(x * 5 + fq)];
                A0 = __hadd2(A0, u2h(v.x)); A1 = __hadd2(A1, u2h(v.y));
                A2 = __hadd2(A2, u2h(v.z)); A3 = __hadd2(A3, u2h(v.w));
            }
        }
    }
    // butterfly-reduce across the 8 edge slots
#pragma unroll
    for (int off = 8; off <= 32; off <<= 1) {
        A0 = __hadd2(A0, u2h((u32)__shfl_xor((int)h2u(A0), off, 64)));
        A1 = __hadd2(A1, u2h((u32)__shfl_xor((int)h2u(A1), off, 64)));
        A2 = __hadd2(A2, u2h((u32)__shfl_xor((int)h2u(A2), off, 64)));
        A3 = __hadd2(A3, u2h((u32)__shfl_xor((int)h2u(A3), off, 64)));
    }

    // bias + log_softmax over 40 features (5 fq groups x 8)
    float4 bva = act ? ((const float4*)b2)[fq * 2 + 0] : make_float4(0.f, 0.f, 0.f, 0.f);
    float4 bvb = act ? ((const float4*)b2)[fq * 2 + 1] : make_float4(0.f, 0.f, 0.f, 0.f);
    float v0 = act ? __low2float(A0)  * dv + bva.x : -INFINITY;
    float v1 = act ? __high2float(A0) * dv + bva.y : -INFINITY;
    float v2 = act ? __low2float(A1)  * dv + bva.z : -INFINITY;
    float v3 = act ? __high2float(A1) * dv + bva.w : -INFINITY;
    float v4 = act ? __low2float(A2)  * dv + bvb.x : -INFINITY;
    float v5 = act ? __high2float(A2) * dv + bvb.y : -INFINITY;
    float v6 = act ? __low2float(A3)  * dv + bvb.z : -INFINITY;
    float v7 = act ? __high2float(A3) * dv + bvb.w : -INFINITY;
    float m = fmaxf(fmaxf(fmaxf(v0, v1), fmaxf(v2, v3)),
                    fmaxf(fmaxf(v4, v5), fmaxf(v6, v7)));
    m = fmaxf(m, __shfl_xor(m, 1, 64));
    m = fmaxf(m, __shfl_xor(m, 2, 64));
    m = fmaxf(m, __shfl_xor(m, 4, 64));
    float ex = 0.f;
    if (act) {
        ex = __expf(v0 - m) + __expf(v1 - m) + __expf(v2 - m) + __expf(v3 - m)
           + __expf(v4 - m) + __expf(v5 - m) + __expf(v6 - m) + __expf(v7 - m);
    }
    ex += __shfl_xor(ex, 1, 64);
    ex += __shfl_xor(ex, 2, 64);
    ex += __shfl_xor(ex, 4, 64);
    float lse = m + __logf(ex);
    if (es == 0 && act) {
        float4 oa = make_float4(v0 - lse, v1 - lse, v2 - lse, v3 - lse);
        float4 ob = make_float4(v4 - lse, v5 - lse, v6 - lse, v7 - lse);
        *(float4*)&out[(u32)(node * 40 + fq * 8 + 0)] = oa;
        *(float4*)&out[(u32)(node * 40 + fq * 8 + 4)] = ob;
    }
}

// ---------------- launch ----------------

extern "C" void kernel_launch(void* const* d_in, const int* in_sizes, int n_in,
                              void* d_out, int out_size, void* d_ws, size_t ws_size,
                              hipStream_t stream) {
    const float* x  = (const float*)d_in[0];
    const float* W1 = (const float*)d_in[1];
    const float* b1 = (const float*)d_in[2];
    const float* W2 = (const float*)d_in[3];
    const float* b2 = (const float*)d_in[4];
    const int* eidx = (const int*)d_in[5];
    const int* srcp = eidx;
    const int* dstp = eidx + N_EDGES;
    float* out = (float*)d_out;

    char* w = (char*)d_ws;
    int* gcur    = (int*)w;   w += sizeof(int) * NB;
    float* dinv  = (float*)w; w += sizeof(float) * N_NODES + 48;  // keep int4 alignment
    int4* meta   = (int4*)w;  w += sizeof(int4) * N_NODES;
    u32* staged  = (u32*)w;   w += sizeof(u32) * (size_t)NB * CAP;       // 8 MB
    int* csr     = (int*)w;   w += sizeof(int) * N_EDGES;                // 6.4 MB
    u16* h1s     = (u16*)w;   w += sizeof(u16) * (size_t)N_NODES * DH;   // f16 [N,64]
    u16* h1f     = (u16*)w;   w += sizeof(u16) * (size_t)N_NODES * DH;   // f16 [N,64]
    u16* h2s     = h1s;  // alias: h1s dead after agg1; h2s is f16 [N,40] compact (8 MB)

    hipMemsetAsync(gcur, 0, sizeof(int) * NB, stream);
    k_bin<<<BIN_BLOCKS, 1024, 0, stream>>>(srcp, dstp, gcur, staged);
    k_csr<<<NB, 256, 0, stream>>>(gcur, staged, csr, meta, dinv);
    k_gemm1<<<(N_NODES + 63) / 64, 256, 0, stream>>>(x, W1, dinv, h1s);
    k_agg1<<<(N_NODES + 3) / 4, 256, 0, stream>>>(h1s, meta, csr, b1, h1f);
    k_gemm2<<<(N_NODES + 63) / 64, 256, 0, stream>>>(h1f, W2, dinv, h2s);
    k_agg2<<<(N_NODES + 3) / 4, 256, 0, stream>>>(h2s, meta, csr, b2, out);
}